// Round 4
// baseline (1259.640 us; speedup 1.0000x reference)
//
#include <hip/hip_runtime.h>
#include <hip/hip_bf16.h>
#include <stdint.h>

typedef unsigned short u16;

#define K_DIM 4096
#define N_DIM 16384

#define BM 256
#define BN 256
#define BK 64
#define NT (K_DIM / BK)  // 64 K-tiles
#define HALF_ELEMS 8192  // 128 rows * 64 cols

typedef __attribute__((ext_vector_type(4))) float f32x4;
typedef __attribute__((ext_vector_type(16))) float f32x16;
typedef __attribute__((ext_vector_type(8))) short bf16x8;

#define GLOAD_LDS16(g, l)                                                      \
  __builtin_amdgcn_global_load_lds(                                            \
      (const __attribute__((address_space(1))) void*)(g),                      \
      (__attribute__((address_space(3))) void*)(l), 16, 0, 0)

#define SFENCE() __builtin_amdgcn_sched_barrier(0)
#define CFENCE() asm volatile("" ::: "memory")
#define BARRIER()                                                              \
  do {                                                                         \
    SFENCE();                                                                  \
    CFENCE();                                                                  \
    __builtin_amdgcn_s_barrier();                                              \
    CFENCE();                                                                  \
    SFENCE();                                                                  \
  } while (0)
#define VMCNT(n) asm volatile("s_waitcnt vmcnt(" #n ")" ::: "memory")
#define LGKMCNT(n) asm volatile("s_waitcnt lgkmcnt(" #n ")" ::: "memory")

// int32 in [-127,127] -> bf16 exact
__device__ __forceinline__ u16 i32_to_bf16(int v) {
  return (u16)(__float_as_uint((float)v) >> 16);
}
__device__ __forceinline__ u16 f32_to_bf16(float f) {
  __hip_bfloat16 h = __float2bfloat16(f);
  return *(u16*)&h;
}

__global__ void wconvert_kernel(const int* __restrict__ w,
                                u16* __restrict__ out, int n4) {
  int idx = blockIdx.x * blockDim.x + threadIdx.x;
  int stride = gridDim.x * blockDim.x;
  const int4* w4 = (const int4*)w;
  ushort4* o4 = (ushort4*)out;
  for (int i = idx; i < n4; i += stride) {
    int4 v = w4[i];
    ushort4 o;
    o.x = i32_to_bf16(v.x);
    o.y = i32_to_bf16(v.y);
    o.z = i32_to_bf16(v.z);
    o.w = i32_to_bf16(v.w);
    o4[i] = o;
  }
}

__global__ void xconvert_kernel(const float* __restrict__ x,
                                u16* __restrict__ out, int n4) {
  int idx = blockIdx.x * blockDim.x + threadIdx.x;
  int stride = gridDim.x * blockDim.x;
  const float4* x4 = (const float4*)x;
  ushort4* o4 = (ushort4*)out;
  for (int i = idx; i < n4; i += stride) {
    float4 v = x4[i];
    ushort4 o;
    o.x = f32_to_bf16(v.x);
    o.y = f32_to_bf16(v.y);
    o.z = f32_to_bf16(v.z);
    o.w = f32_to_bf16(v.w);
    o4[i] = o;
  }
}

// Stage one half-tile (128 rows x 64 k, bf16, 16KB) global->LDS.
// LDS dest LINEAR (gload_lds writes base + lane*16); the st-swizzle is applied
// by permuting the GLOBAL source 16B-unit:
//   stored unit at LDS slot (row, lin) = lin ^ sigma(row),
//   sigma(row) = (row ^ (row>>2)) & 7   (r2-verified: 0 bank conflicts)
__device__ __forceinline__ void stage_half(const u16* __restrict__ src,
                                           u16* lds_half, int t) {
#pragma unroll
  for (int c = 0; c < 2; ++c) {
    int e = c * 4096 + t * 8;                 // per-lane linear u16 offset
    int row = c * 64 + (t >> 3);              // 0..127
    int usw = (t & 7) ^ (((t >> 3) ^ (t >> 5)) & 7);  // lin ^ sigma(row)
    int base = __builtin_amdgcn_readfirstlane(e);  // wave-uniform LDS base
    GLOAD_LDS16(src + (size_t)row * K_DIM + usw * 8, lds_half + base);
  }
}

// swizzled fragment read: tile row r (0..255), 16B-unit u (0..7)
__device__ __forceinline__ bf16x8 frag(const u16* sbuf, int r, int u) {
  return *(const bf16x8*)&sbuf[r * 64 + ((u ^ ((r ^ (r >> 2)) & 7)) << 3)];
}

// C[M,N] = X[M,K] * W[N,K]^T ; y = acc*scale[n] + bias[n], f32 out.
// 256x256 tile, BK=64, 8 waves (2M x 4N), per-wave 128x64 output,
// 32x32x16 MFMA (4x2 tile grid, acc = 8 x f32x16).
//
// K-STEP REGISTER PIPELINE (this round's change): each BK=64 tile = 4 ks-steps
// of {6 ds_read_b128, 8 MFMA}. Two 6-frag register buffers (x, y) rotate so
// the reads for step s+1 are issued BEFORE the MFMAs of step s -> each wave's
// LDS-read drain hides under its own MFMA window, keeping the (shared) LDS
// pipe and MFMA pipe simultaneously busy instead of alternating in lockstep
// bursts (r0-r3 measured: LDS 4608cy + MFMA 4130cy additive per iter).
//
// Barrier skeleton per tile (2 barriers):
//   h0: read s1 -> y ; MFMA s0 (x) ; read s2 -> x ; MFMA s1 (y) ;
//       read s3 -> y ; lgkmcnt(0) ; BARRIER          (all tile-u reads drained)
//   h1: stage tile u+2 -> this buffer (whole tile; provably dead) ;
//       MFMA s2 (x) ; read (u+1,s0) -> x from other buffer ; MFMA s3 (y) ;
//       vmcnt(0) ; lgkmcnt(0) ; BARRIER
// Safety: every wave's ds_reads of a buffer are lgkm-drained before the
// barrier that precedes any overwrite-stage of it; staged-tile residency for
// reads is guaranteed by vmcnt(0)+barrier at each tile end (collective).
__global__ __launch_bounds__(512, 2) void qgemm8_kernel(
    const u16* __restrict__ Xb,   // bf16 [M][K]
    const u16* __restrict__ Wb,   // bf16 [N][K]
    const float* __restrict__ S,  // f32 [N]
    const float* __restrict__ Bv, // f32 [N]
    float* __restrict__ Y,        // f32 [M][N]
    int M) {
  extern __shared__ u16 lds[];
  u16* sA0 = lds;             // buf0 A [256][64]
  u16* sB0 = lds + 16384;     // buf0 B
  u16* sA1 = lds + 32768;     // buf1 A
  u16* sB1 = lds + 49152;     // buf1 B

  const int t = threadIdx.x;
  // XCD-aware swizzle (nwg = 2048, divisible by 8)
  const int bid = blockIdx.x;
  const int cpx = gridDim.x >> 3;
  const int swz = (bid & 7) * cpx + (bid >> 3);
  const int n0 = (swz & 63) * BN;  // 64 n-blocks
  const int m0 = (swz >> 6) * BM;

  const int lane = t & 63;
  const int wid = t >> 6;      // 0..7
  const int r32 = lane & 31;   // row/col within 32x32 tile
  const int hi1 = lane >> 5;   // k-half selector (0..1)
  const int wm = wid >> 2;     // 0..1 -> rows wm*128..+127
  const int wn = wid & 3;      // 0..3 -> cols wn*64..+63

  const u16* Asrc = Xb + (size_t)m0 * K_DIM;
  const u16* Bsrc = Wb + (size_t)n0 * K_DIM;

  f32x16 acc[4][2] = {};       // [row-tile 0..3][col-tile 0..1]
  bf16x8 xa[4], xb[2];         // ks-step frag buffer X
  bf16x8 ya[4], yb[2];         // ks-step frag buffer Y

  // 32x32x16 operand layout: lane holds row/col = lane&31,
  // k = (lane>>5)*8 + j  -> 16B unit u = ks*2 + hi1 within the 64-k row.
#define READ_STEP(FA, FB, sa, sb, U)                                           \
  do {                                                                         \
    _Pragma("unroll") for (int rt = 0; rt < 4; ++rt)                           \
        FA[rt] = frag(sa, wm * 128 + rt * 32 + r32, (U) * 2 + hi1);            \
    _Pragma("unroll") for (int ct = 0; ct < 2; ++ct)                           \
        FB[ct] = frag(sb, wn * 64 + ct * 32 + r32, (U) * 2 + hi1);             \
  } while (0)

#define MFMA_STEP(FA, FB)                                                      \
  do {                                                                         \
    __builtin_amdgcn_s_setprio(1);                                             \
    _Pragma("unroll") for (int rt = 0; rt < 4; ++rt)                           \
    _Pragma("unroll") for (int ct = 0; ct < 2; ++ct)                           \
        acc[rt][ct] = __builtin_amdgcn_mfma_f32_32x32x16_bf16(                 \
            FA[rt], FB[ct], acc[rt][ct], 0, 0, 0);                             \
    __builtin_amdgcn_s_setprio(0);                                             \
  } while (0)

#define STAGE_TILE(KOFF, sa, sb)                                               \
  do {                                                                         \
    stage_half(Bsrc + (KOFF), sb, t);                                          \
    stage_half(Bsrc + 128 * K_DIM + (KOFF), sb + HALF_ELEMS, t);               \
    stage_half(Asrc + (KOFF), sa, t);                                          \
    stage_half(Asrc + 128 * K_DIM + (KOFF), sa + HALF_ELEMS, t);               \
  } while (0)

// One K-tile. Entry invariant: xa/xb hold (this tile, ks0).
// Exit invariant: xa/xb hold (next tile, ks0).
#define TILE_BODY(SA, SB, SAn, SBn, KST, ST)                                   \
  do {                                                                         \
    READ_STEP(ya, yb, SA, SB, 1);                                              \
    MFMA_STEP(xa, xb); /* ks0 */                                               \
    READ_STEP(xa, xb, SA, SB, 2);                                              \
    MFMA_STEP(ya, yb); /* ks1 */                                               \
    READ_STEP(ya, yb, SA, SB, 3);                                              \
    LGKMCNT(0);        /* all reads of this buffer drained (pre-stage WAR) */  \
    BARRIER();                                                                 \
    if (ST) STAGE_TILE(KST, SA, SB); /* buffer dead: overwrite whole tile */   \
    MFMA_STEP(xa, xb); /* ks2 */                                               \
    READ_STEP(xa, xb, SAn, SBn, 0); /* next tile ks0 (resident via vmcnt) */   \
    MFMA_STEP(ya, yb); /* ks3 */                                               \
    VMCNT(0);          /* staged tile landed before anyone reads it */         \
    LGKMCNT(0);        /* next-tile reads drained (WAR vs next stage) */       \
    BARRIER();                                                                 \
  } while (0)

  // ---- prologue: stage tiles 0 and 1 whole, drain, first frags
  STAGE_TILE(0, sA0, sB0);
  STAGE_TILE(BK, sA1, sB1);
  VMCNT(0);
  BARRIER();
  READ_STEP(xa, xb, sA0, sB0, 0);  // tile 0, ks0

  // ---- main loop: 2 tiles per j (buffer parity static)
  for (int j = 0; j < NT / 2; ++j) {
    const bool st = (j < NT / 2 - 1);
    TILE_BODY(sA0, sB0, sA1, sB1, (2 * j + 2) * BK, st);
    TILE_BODY(sA1, sB1, sA0, sB0, (2 * j + 3) * BK, st);
  }

  // ---- epilogue: y = acc * scale[n] + bias[n], f32 store
  // 32x32 C/D layout: col = lane&31, row = (reg&3) + 8*(reg>>2) + 4*(lane>>5)
#pragma unroll
  for (int ct = 0; ct < 2; ++ct) {
    int n = n0 + wn * 64 + ct * 32 + r32;
    float sc = S[n];
    float bv = Bv[n];
#pragma unroll
    for (int mi = 0; mi < 4; ++mi) {
#pragma unroll
      for (int reg = 0; reg < 16; ++reg) {
        int m = m0 + wm * 128 + mi * 32 + (reg & 3) + 8 * (reg >> 2) + 4 * hi1;
        Y[(size_t)m * N_DIM + n] = acc[mi][ct][reg] * sc + bv;
      }
    }
  }
#undef TILE_BODY
#undef STAGE_TILE
#undef READ_STEP
#undef MFMA_STEP
}

// ---- fallback (ws too small): serial 128^2 with inline convert
__global__ __launch_bounds__(256) void qgemm_fb_kernel(
    const float* __restrict__ Xf, const int* __restrict__ Wi,
    const float* __restrict__ S, const float* __restrict__ Bv,
    float* __restrict__ Y, int M) {
  __shared__ u16 As[128 * 64];
  __shared__ u16 Bs[128 * 64];
  const int t = threadIdx.x;
  const int bid = blockIdx.x;
  const int n0 = (bid & 127) * 128;
  const int m0 = (bid >> 7) * 128;
  const int lane = t & 63;
  const int wid = t >> 6;
  const int r16 = lane & 15;
  const int hi4 = lane >> 4;
  const int wm = wid >> 1;
  const int wn = wid & 1;
  f32x4 acc[4][4] = {};
  for (int kt = 0; kt < K_DIM; kt += 64) {
#pragma unroll
    for (int c = 0; c < 8; ++c) {
      int h = c * 1024 + t * 4;
      int row = h >> 6;
      int col = h & 63;
      float4 v = *(const float4*)(Xf + (size_t)(m0 + row) * K_DIM + kt + col);
      ushort4 o;
      o.x = f32_to_bf16(v.x); o.y = f32_to_bf16(v.y);
      o.z = f32_to_bf16(v.z); o.w = f32_to_bf16(v.w);
      *(ushort4*)&As[h] = o;
      int4 w = *(const int4*)(Wi + (size_t)(n0 + row) * K_DIM + kt + col);
      ushort4 ow;
      ow.x = i32_to_bf16(w.x); ow.y = i32_to_bf16(w.y);
      ow.z = i32_to_bf16(w.z); ow.w = i32_to_bf16(w.w);
      *(ushort4*)&Bs[h] = ow;
    }
    __syncthreads();
#pragma unroll
    for (int kk = 0; kk < 64; kk += 32) {
      bf16x8 af[4], bf[4];
#pragma unroll
      for (int mi = 0; mi < 4; ++mi)
        af[mi] = *(const bf16x8*)&As[(wm * 64 + mi * 16 + r16) * 64 + kk + hi4 * 8];
#pragma unroll
      for (int ni = 0; ni < 4; ++ni)
        bf[ni] = *(const bf16x8*)&Bs[(wn * 64 + ni * 16 + r16) * 64 + kk + hi4 * 8];
#pragma unroll
      for (int mi = 0; mi < 4; ++mi)
#pragma unroll
        for (int ni = 0; ni < 4; ++ni)
          acc[mi][ni] = __builtin_amdgcn_mfma_f32_16x16x32_bf16(
              af[mi], bf[ni], acc[mi][ni], 0, 0, 0);
    }
    __syncthreads();
  }
#pragma unroll
  for (int ni = 0; ni < 4; ++ni) {
    int n = n0 + wn * 64 + ni * 16 + r16;
    float sc = S[n], bv = Bv[n];
#pragma unroll
    for (int mi = 0; mi < 4; ++mi)
#pragma unroll
      for (int r = 0; r < 4; ++r) {
        int m = m0 + wm * 64 + mi * 16 + hi4 * 4 + r;
        Y[(size_t)m * N_DIM + n] = acc[mi][ni][r] * sc + bv;
      }
  }
}

extern "C" void kernel_launch(void* const* d_in, const int* in_sizes, int n_in,
                              void* d_out, int out_size, void* d_ws,
                              size_t ws_size, hipStream_t stream) {
  const float* x = (const float*)d_in[0];  // fp16 promoted to f32 by harness
  const int* wgt = (const int*)d_in[1];    // int8 promoted to int32
  const float* s = (const float*)d_in[2];
  const float* b = (const float*)d_in[3];
  float* y = (float*)d_out;

  const int M = in_sizes[0] / K_DIM;  // 8192
  const size_t wcount = (size_t)N_DIM * K_DIM;
  const size_t xcount = (size_t)in_sizes[0];
  const size_t need = (wcount + xcount) * sizeof(u16);

  if (ws_size >= need && (M % BM) == 0) {
    u16* wb = (u16*)d_ws;
    u16* xb = wb + wcount;
    wconvert_kernel<<<2048, 256, 0, stream>>>(wgt, wb, (int)(wcount / 4));
    xconvert_kernel<<<2048, 256, 0, stream>>>(x, xb, (int)(xcount / 4));
    hipFuncSetAttribute((const void*)qgemm8_kernel,
                        hipFuncAttributeMaxDynamicSharedMemorySize, 131072);
    dim3 grid((N_DIM / BN) * (M / BM));  // 2048
    qgemm8_kernel<<<grid, 512, 131072, stream>>>(xb, wb, s, b, y, M);
  } else {
    dim3 grid((N_DIM / 128) * (M / 128));
    qgemm_fb_kernel<<<grid, 256, 0, stream>>>(x, wgt, s, b, y, M);
  }
}

// Round 5
// 1175.449 us; speedup vs baseline: 1.0716x; 1.0716x over previous
//
#include <hip/hip_runtime.h>
#include <hip/hip_bf16.h>
#include <stdint.h>

typedef unsigned short u16;

#define K_DIM 4096
#define N_DIM 16384

// ---- 128x128 / 2-blocks-per-CU geometry
#define BMT 128
#define BNT 128
#define BK 64
#define NT (K_DIM / BK)      // 64 K-tiles
#define TILE_ELEMS 8192      // 128 rows * 64 cols (u16)

typedef __attribute__((ext_vector_type(4))) float f32x4;
typedef __attribute__((ext_vector_type(16))) float f32x16;
typedef __attribute__((ext_vector_type(8))) short bf16x8;

#define GLOAD_LDS16(g, l)                                                      \
  __builtin_amdgcn_global_load_lds(                                            \
      (const __attribute__((address_space(1))) void*)(g),                      \
      (__attribute__((address_space(3))) void*)(l), 16, 0, 0)

#define SFENCE() __builtin_amdgcn_sched_barrier(0)
#define CFENCE() asm volatile("" ::: "memory")
#define BARRIER()                                                              \
  do {                                                                         \
    SFENCE();                                                                  \
    CFENCE();                                                                  \
    __builtin_amdgcn_s_barrier();                                              \
    CFENCE();                                                                  \
    SFENCE();                                                                  \
  } while (0)
#define VMCNT(n) asm volatile("s_waitcnt vmcnt(" #n ")" ::: "memory")
#define LGKMCNT(n) asm volatile("s_waitcnt lgkmcnt(" #n ")" ::: "memory")

// int32 in [-127,127] -> bf16 exact
__device__ __forceinline__ u16 i32_to_bf16(int v) {
  return (u16)(__float_as_uint((float)v) >> 16);
}
__device__ __forceinline__ u16 f32_to_bf16(float f) {
  __hip_bfloat16 h = __float2bfloat16(f);
  return *(u16*)&h;
}

__global__ void wconvert_kernel(const int* __restrict__ w,
                                u16* __restrict__ out, int n4) {
  int idx = blockIdx.x * blockDim.x + threadIdx.x;
  int stride = gridDim.x * blockDim.x;
  const int4* w4 = (const int4*)w;
  ushort4* o4 = (ushort4*)out;
  for (int i = idx; i < n4; i += stride) {
    int4 v = w4[i];
    ushort4 o;
    o.x = i32_to_bf16(v.x);
    o.y = i32_to_bf16(v.y);
    o.z = i32_to_bf16(v.z);
    o.w = i32_to_bf16(v.w);
    o4[i] = o;
  }
}

__global__ void xconvert_kernel(const float* __restrict__ x,
                                u16* __restrict__ out, int n4) {
  int idx = blockIdx.x * blockDim.x + threadIdx.x;
  int stride = gridDim.x * blockDim.x;
  const float4* x4 = (const float4*)x;
  ushort4* o4 = (ushort4*)out;
  for (int i = idx; i < n4; i += stride) {
    float4 v = x4[i];
    ushort4 o;
    o.x = f32_to_bf16(v.x);
    o.y = f32_to_bf16(v.y);
    o.z = f32_to_bf16(v.z);
    o.w = f32_to_bf16(v.w);
    o4[i] = o;
  }
}

// Stage one operand tile (128 rows x 64 k, bf16, 16KB) global->LDS with
// 256 threads (4 gload_lds per thread). LDS dest LINEAR (gload_lds writes
// base + lane*16); the swizzle permutes the GLOBAL source 16B-unit:
//   stored unit at LDS slot (row, lin) = lin ^ sigma(row),
//   sigma(row) = (row ^ (row>>2)) & 7   (r2-verified: 0 bank conflicts)
__device__ __forceinline__ void stage_tile(const u16* __restrict__ src,
                                           u16* lds_tile, int t) {
#pragma unroll
  for (int c = 0; c < 4; ++c) {
    int e = c * 2048 + t * 8;                 // per-lane linear u16 offset
    int row = c * 32 + (t >> 3);              // 0..127
    int usw = (t & 7) ^ (((t >> 3) ^ (t >> 5)) & 7);  // lin ^ sigma(row)
    int base = __builtin_amdgcn_readfirstlane(e);  // wave-uniform LDS base
    GLOAD_LDS16(src + (size_t)row * K_DIM + usw * 8, lds_tile + base);
  }
}

// swizzled fragment read: tile row r (0..127), 16B-unit u (0..7)
__device__ __forceinline__ bf16x8 frag(const u16* sbuf, int r, int u) {
  return *(const bf16x8*)&sbuf[r * 64 + ((u ^ ((r ^ (r >> 2)) & 7)) << 3)];
}

// C[M,N] = X[M,K] * W[N,K]^T ; y = acc*scale[n] + bias[n], f32 out.
//
// THIS ROUND: 2 independent blocks per CU (TLP overlap of LDS and MFMA pipes).
// r0-r3 plateaued at ~1010us with 1 block/CU (128KB LDS): all 8 waves share
// one barrier domain, so LDS-read windows and MFMA windows strictly
// alternate (measured: iter time = LDS-pipe-time + MFMA-pipe-time, additive).
// 128x128 tile, 256 threads (4 waves, 2x2, per-wave 64x64), BK=64 dbuf ->
// LDS = 64KB -> 2 blocks/CU, ~150 VGPR -> 2 waves/SIMD. While one block is
// in its read/barrier window the other feeds the matrix pipe.
//
// Per-tile skeleton (verified discipline from r0-r3, counted vmcnt - no
// main-loop drain-0, the r4 mistake):
//   READS(buf[cur]) ; lgkmcnt(0) ; BARRIER          (WAR: reads drained)
//   stage(t+2 -> buf[cur])                          (buffer dead everywhere)
//   MFMA x16                                        (stage hides under MFMA
//                                                    + all of tile t+1)
//   vmcnt(8) ; BARRIER                              (RAW: t+1 resident)
__global__ __launch_bounds__(256, 2) void qgemm8_kernel(
    const u16* __restrict__ Xb,   // bf16 [M][K]
    const u16* __restrict__ Wb,   // bf16 [N][K]
    const float* __restrict__ S,  // f32 [N]
    const float* __restrict__ Bv, // f32 [N]
    float* __restrict__ Y,        // f32 [M][N]
    int M) {
  extern __shared__ u16 lds[];
  u16* sA0 = lds;              // buf0 A [128][64]
  u16* sB0 = lds + 8192;       // buf0 B
  u16* sA1 = lds + 16384;      // buf1 A
  u16* sB1 = lds + 24576;      // buf1 B

  const int t = threadIdx.x;
  // XCD chunk + 4m x 16n grouping for L2 reuse:
  //   per 64-block cohort: 4 A panels (4MB) + 16 B panels -> A L2-hot,
  //   B panels read by 2 consecutive groups then never again per XCD.
  const int bid = blockIdx.x;
  const int xcd = bid & 7;
  const int l = bid >> 3;            // [0, nwg/8)
  const int nmx = M >> 10;           // m-blocks per XCD chunk (M/1024)
  const int gpm = nmx >> 2;          // m-groups (of 4) per chunk
  const int g = l >> 6;              // 64-block group (4m x 16n)
  const int w = l & 63;
  const int lm = w & 3;
  const int ln = w >> 2;
  const int gm = g % gpm;
  const int gn = g / gpm;
  const int m0 = (xcd * nmx + gm * 4 + lm) * BMT;
  const int n0 = (gn * 16 + ln) * BNT;

  const int lane = t & 63;
  const int wid = t >> 6;      // 0..3
  const int r32 = lane & 31;   // row/col within 32x32 tile
  const int hi1 = lane >> 5;   // k-half selector (0..1)
  const int wm = wid >> 1;     // 0..1 -> rows wm*64..+63
  const int wn = wid & 1;      // 0..1 -> cols wn*64..+63

  const u16* Asrc = Xb + (size_t)m0 * K_DIM;
  const u16* Bsrc = Wb + (size_t)n0 * K_DIM;

  f32x16 acc[2][2] = {};       // [row-tile][col-tile] of 32x32
  bf16x8 aT[8], bT[8];         // [rt*4+ks] / [ct*4+ks]

  // 32x32x16 operand layout (r2-verified): lane holds row/col = lane&31,
  // k = (lane>>5)*8 + j  -> 16B unit u = ks*2 + hi1 within the 64-k row.
#define READS(sa, sb)                                                          \
  do {                                                                         \
    _Pragma("unroll") for (int rt = 0; rt < 2; ++rt)                           \
    _Pragma("unroll") for (int ks = 0; ks < 4; ++ks)                           \
        aT[rt * 4 + ks] = frag(sa, wm * 64 + rt * 32 + r32, ks * 2 + hi1);     \
    _Pragma("unroll") for (int ct = 0; ct < 2; ++ct)                           \
    _Pragma("unroll") for (int ks = 0; ks < 4; ++ks)                           \
        bT[ct * 4 + ks] = frag(sb, wn * 64 + ct * 32 + r32, ks * 2 + hi1);     \
  } while (0)

#define MFMA_ALL()                                                             \
  do {                                                                         \
    __builtin_amdgcn_s_setprio(1);                                             \
    _Pragma("unroll") for (int ks = 0; ks < 4; ++ks)                           \
    _Pragma("unroll") for (int rt = 0; rt < 2; ++rt)                           \
    _Pragma("unroll") for (int ct = 0; ct < 2; ++ct)                           \
        acc[rt][ct] = __builtin_amdgcn_mfma_f32_32x32x16_bf16(                 \
            aT[rt * 4 + ks], bT[ct * 4 + ks], acc[rt][ct], 0, 0, 0);           \
    __builtin_amdgcn_s_setprio(0);                                             \
  } while (0)

#define STAGE(KOFF, sa, sb)                                                    \
  do {                                                                         \
    stage_tile(Asrc + (KOFF), sa, t);                                          \
    stage_tile(Bsrc + (KOFF), sb, t);                                          \
  } while (0)

// One K-tile: entry invariant: buf holds tile resident; 8 vmem outstanding
// (next tile's stage). Exit: next tile resident; 8 outstanding (tile+2).
#define TILE_BODY(SA, SB, TN, ST)                                              \
  do {                                                                         \
    READS(SA, SB);                                                             \
    LGKMCNT(0);  /* this wave's reads serviced (WAR before stage) */           \
    BARRIER();   /* all waves done reading this buffer */                      \
    if (ST) STAGE((size_t)(TN) * BK, SA, SB);                                  \
    MFMA_ALL();                                                                \
    if (ST) {                                                                  \
      VMCNT(8);  /* drain tile+1's 8, keep tile+2's 8 in flight */             \
    } else {                                                                   \
      VMCNT(0);  /* tail: drain everything */                                  \
    }                                                                          \
    BARRIER();   /* tile+1 resident for all waves */                           \
  } while (0)

  // ---- prologue: stage tiles 0 and 1
  STAGE(0, sA0, sB0);
  STAGE(BK, sA1, sB1);
  VMCNT(8);  // tile 0's 8 landed; tile 1's 8 in flight
  BARRIER();

  // ---- main loop: 2 tiles per j (static buffer parity)
  for (int j = 0; j < NT / 2; ++j) {
    const bool st0 = (2 * j + 2) < NT;
    const bool st1 = (2 * j + 3) < NT;
    TILE_BODY(sA0, sB0, 2 * j + 2, st0);
    TILE_BODY(sA1, sB1, 2 * j + 3, st1);
  }

  // ---- epilogue: y = acc * scale[n] + bias[n], f32 store
  // 32x32 C/D layout (r2-verified): col = lane&31,
  // row = (reg&3) + 8*(reg>>2) + 4*(lane>>5)
#pragma unroll
  for (int ct = 0; ct < 2; ++ct) {
    int n = n0 + wn * 64 + ct * 32 + r32;
    float sc = S[n];
    float bv = Bv[n];
#pragma unroll
    for (int rt = 0; rt < 2; ++rt) {
#pragma unroll
      for (int reg = 0; reg < 16; ++reg) {
        int m = m0 + wm * 64 + rt * 32 + (reg & 3) + 8 * (reg >> 2) + 4 * hi1;
        Y[(size_t)m * N_DIM + n] = acc[rt][ct][reg] * sc + bv;
      }
    }
  }
#undef TILE_BODY
#undef STAGE
#undef READS
#undef MFMA_ALL
}

// ---- fallback (ws too small / shape mismatch): serial 128^2 with inline
// convert
__global__ __launch_bounds__(256) void qgemm_fb_kernel(
    const float* __restrict__ Xf, const int* __restrict__ Wi,
    const float* __restrict__ S, const float* __restrict__ Bv,
    float* __restrict__ Y, int M) {
  __shared__ u16 As[128 * 64];
  __shared__ u16 Bs[128 * 64];
  const int t = threadIdx.x;
  const int bid = blockIdx.x;
  const int n0 = (bid & 127) * 128;
  const int m0 = (bid >> 7) * 128;
  const int lane = t & 63;
  const int wid = t >> 6;
  const int r16 = lane & 15;
  const int hi4 = lane >> 4;
  const int wm = wid >> 1;
  const int wn = wid & 1;
  f32x4 acc[4][4] = {};
  for (int kt = 0; kt < K_DIM; kt += 64) {
#pragma unroll
    for (int c = 0; c < 8; ++c) {
      int h = c * 1024 + t * 4;
      int row = h >> 6;
      int col = h & 63;
      float4 v = *(const float4*)(Xf + (size_t)(m0 + row) * K_DIM + kt + col);
      ushort4 o;
      o.x = f32_to_bf16(v.x); o.y = f32_to_bf16(v.y);
      o.z = f32_to_bf16(v.z); o.w = f32_to_bf16(v.w);
      *(ushort4*)&As[h] = o;
      int4 w = *(const int4*)(Wi + (size_t)(n0 + row) * K_DIM + kt + col);
      ushort4 ow;
      ow.x = i32_to_bf16(w.x); ow.y = i32_to_bf16(w.y);
      ow.z = i32_to_bf16(w.z); ow.w = i32_to_bf16(w.w);
      *(ushort4*)&Bs[h] = ow;
    }
    __syncthreads();
#pragma unroll
    for (int kk = 0; kk < 64; kk += 32) {
      bf16x8 af[4], bf[4];
#pragma unroll
      for (int mi = 0; mi < 4; ++mi)
        af[mi] = *(const bf16x8*)&As[(wm * 64 + mi * 16 + r16) * 64 + kk + hi4 * 8];
#pragma unroll
      for (int ni = 0; ni < 4; ++ni)
        bf[ni] = *(const bf16x8*)&Bs[(wn * 64 + ni * 16 + r16) * 64 + kk + hi4 * 8];
#pragma unroll
      for (int mi = 0; mi < 4; ++mi)
#pragma unroll
        for (int ni = 0; ni < 4; ++ni)
          acc[mi][ni] = __builtin_amdgcn_mfma_f32_16x16x32_bf16(
              af[mi], bf[ni], acc[mi][ni], 0, 0, 0);
    }
    __syncthreads();
  }
#pragma unroll
  for (int ni = 0; ni < 4; ++ni) {
    int n = n0 + wn * 64 + ni * 16 + r16;
    float sc = S[n], bv = Bv[n];
#pragma unroll
    for (int mi = 0; mi < 4; ++mi)
#pragma unroll
      for (int r = 0; r < 4; ++r) {
        int m = m0 + wm * 64 + mi * 16 + hi4 * 4 + r;
        Y[(size_t)m * N_DIM + n] = acc[mi][ni][r] * sc + bv;
      }
  }
}

extern "C" void kernel_launch(void* const* d_in, const int* in_sizes, int n_in,
                              void* d_out, int out_size, void* d_ws,
                              size_t ws_size, hipStream_t stream) {
  const float* x = (const float*)d_in[0];  // fp16 promoted to f32 by harness
  const int* wgt = (const int*)d_in[1];    // int8 promoted to int32
  const float* s = (const float*)d_in[2];
  const float* b = (const float*)d_in[3];
  float* y = (float*)d_out;

  const int M = in_sizes[0] / K_DIM;  // 8192
  const size_t wcount = (size_t)N_DIM * K_DIM;
  const size_t xcount = (size_t)in_sizes[0];
  const size_t need = (wcount + xcount) * sizeof(u16);

  // fast path needs: workspace for bf16 copies; M divisible by 4096 so the
  // 8-XCD x (4m x 16n) group mapping covers the grid bijectively.
  if (ws_size >= need && (M % 4096) == 0) {
    u16* wb = (u16*)d_ws;
    u16* xb = wb + wcount;
    wconvert_kernel<<<2048, 256, 0, stream>>>(wgt, wb, (int)(wcount / 4));
    xconvert_kernel<<<2048, 256, 0, stream>>>(x, xb, (int)(xcount / 4));
    hipFuncSetAttribute((const void*)qgemm8_kernel,
                        hipFuncAttributeMaxDynamicSharedMemorySize, 65536);
    dim3 grid((N_DIM / BNT) * (M / BMT));  // 128 * (M/128) = 8192
    qgemm8_kernel<<<grid, 256, 65536, stream>>>(xb, wb, s, b, y, M);
  } else {
    dim3 grid((N_DIM / 128) * (M / 128));
    qgemm_fb_kernel<<<grid, 256, 0, stream>>>(x, wgt, s, b, y, M);
  }
}

// Round 6
// 1160.959 us; speedup vs baseline: 1.0850x; 1.0125x over previous
//
#include <hip/hip_runtime.h>
#include <hip/hip_bf16.h>
#include <stdint.h>

typedef unsigned short u16;

#define K_DIM 4096
#define N_DIM 16384

// ---- 256^2 tile, BK=32, triple-buffered, ks-pipelined
#define BM 256
#define BN 256
#define BK 32
#define NT (K_DIM / BK)      // 128 K-tiles

typedef __attribute__((ext_vector_type(4))) float f32x4;
typedef __attribute__((ext_vector_type(16))) float f32x16;
typedef __attribute__((ext_vector_type(8))) short bf16x8;

#define GLOAD_LDS16(g, l)                                                      \
  __builtin_amdgcn_global_load_lds(                                            \
      (const __attribute__((address_space(1))) void*)(g),                      \
      (__attribute__((address_space(3))) void*)(l), 16, 0, 0)

#define CFENCE() asm volatile("" ::: "memory")
// Light barrier: compiler memory fence + s_barrier, NO sched_barrier pins
// (let the compiler keep its fine-grained counted-lgkmcnt scheduling).
#define BARRIER()                                                              \
  do {                                                                         \
    CFENCE();                                                                  \
    __builtin_amdgcn_s_barrier();                                              \
    CFENCE();                                                                  \
  } while (0)
#define VMCNT(n) asm volatile("s_waitcnt vmcnt(" #n ")" ::: "memory")
#define LGKMCNT(n) asm volatile("s_waitcnt lgkmcnt(" #n ")" ::: "memory")

// int32 in [-127,127] -> bf16 exact
__device__ __forceinline__ u16 i32_to_bf16(int v) {
  return (u16)(__float_as_uint((float)v) >> 16);
}
__device__ __forceinline__ u16 f32_to_bf16(float f) {
  __hip_bfloat16 h = __float2bfloat16(f);
  return *(u16*)&h;
}

__global__ void wconvert_kernel(const int* __restrict__ w,
                                u16* __restrict__ out, int n4) {
  int idx = blockIdx.x * blockDim.x + threadIdx.x;
  int stride = gridDim.x * blockDim.x;
  const int4* w4 = (const int4*)w;
  ushort4* o4 = (ushort4*)out;
  for (int i = idx; i < n4; i += stride) {
    int4 v = w4[i];
    ushort4 o;
    o.x = i32_to_bf16(v.x);
    o.y = i32_to_bf16(v.y);
    o.z = i32_to_bf16(v.z);
    o.w = i32_to_bf16(v.w);
    o4[i] = o;
  }
}

__global__ void xconvert_kernel(const float* __restrict__ x,
                                u16* __restrict__ out, int n4) {
  int idx = blockIdx.x * blockDim.x + threadIdx.x;
  int stride = gridDim.x * blockDim.x;
  const float4* x4 = (const float4*)x;
  ushort4* o4 = (ushort4*)out;
  for (int i = idx; i < n4; i += stride) {
    float4 v = x4[i];
    ushort4 o;
    o.x = f32_to_bf16(v.x);
    o.y = f32_to_bf16(v.y);
    o.z = f32_to_bf16(v.z);
    o.w = f32_to_bf16(v.w);
    o4[i] = o;
  }
}

// ---- BK=32 paired-row LDS layout --------------------------------------------
// A/B tile = 256 rows x 32 k (bf16, 16KB). Storage: 128 "storage rows" (sr)
// of 8 x 16B units: unit holds (tile row = sr + 128*band, k-unit = kl) where
// logical unit usl = kl | (band<<2), physical unit usp = usl ^ sigma(sr),
// sigma(sr) = (sr ^ (sr>>2)) & 7  -- identical XOR geometry to the r2-verified
// conflict-free layout (row stride 128B, 8 units, sigma spreads both
// consecutive and stride-4 crossbar phases).
// Staged LINEARLY by gload_lds (base + lane*16); the swizzle is applied by
// permuting the GLOBAL source address per lane.
__device__ __forceinline__ void stage32(const u16* __restrict__ src,
                                        u16* ldsb, int t) {
#pragma unroll
  for (int c = 0; c < 2; ++c) {
    int e = c * 4096 + t * 8;                       // linear u16 offset
    int sig = ((t >> 3) ^ (t >> 5)) & 7;            // sigma(sr), c drops out
    int usl = (t & 7) ^ sig;                        // logical unit stored here
    int row = c * 64 + (t >> 3) + ((usl >> 2) << 7);  // sr + 128*band
    int kl = usl & 3;
    int base = __builtin_amdgcn_readfirstlane(e);   // wave-uniform LDS base
    GLOAD_LDS16(src + (size_t)row * K_DIM + kl * 8, ldsb + base);
  }
}

// fragment read: tile row r (0..255), k-unit ku (0..3)
__device__ __forceinline__ bf16x8 frag32(const u16* sbuf, int r, int ku) {
  int sr = r & 127;
  int usl = ku | ((r >> 7) << 2);
  int usp = usl ^ ((sr ^ (sr >> 2)) & 7);
  return *(const bf16x8*)&sbuf[sr * 64 + usp * 8];
}

// C[M,N] = X[M,K] * W[N,K]^T ; y = acc*scale[n] + bias[n], f32 out.
// 256x256 tile, BK=32, 8 waves (2M x 4N), per-wave 128x64, 32x32x16 MFMA.
//
// KS-PIPELINED TRIPLE-BUFFER (this round): r0-r3 measured LDS-read time and
// MFMA time ADDITIVE (~2300 + ~2070 cyc per K-tile-pair) because every
// phase's full frag set must land before its first MFMA. Here each tile
// interval issues reads for ks1 BEFORE the ks0 MFMAs, so the LDS drain hides
// under the matrix pipe; 3 LDS buffers make the stage choreography
// one-barrier-per-tile with COUNTED vmcnt (r4's regression was its per-tile
// vmcnt(0) drain -- never repeated here: steady state keeps 4 loads in
// flight, drain-0 only in the last 2 tiles).
//
// Interval for tile u (reads buf[u%3], stages tile u+2 -> buf[(u+2)%3],
// which holds tile u-1, dead since barrier u-1):
//   stage(u+2); read ks0->X; read ks1->Y; MFMA(X); MFMA(Y);
//   lgkmcnt(0)            (WAR airtight even if MFMAs sink past barrier)
//   vmcnt(4)              (tile u+1 resident; u+2's 4 stay in flight)
//   barrier
__global__ __launch_bounds__(512, 2) void qgemm8_kernel(
    const u16* __restrict__ Xg,   // bf16 [M][K]
    const u16* __restrict__ Wg,   // bf16 [N][K]
    const float* __restrict__ S,  // f32 [N]
    const float* __restrict__ Bv, // f32 [N]
    float* __restrict__ Y,        // f32 [M][N]
    int M) {
  extern __shared__ u16 lds[];
  u16* A0_ = lds;             // buf0 A (16KB = 8192 u16)
  u16* B0_ = lds + 8192;
  u16* A1_ = lds + 16384;
  u16* B1_ = lds + 24576;
  u16* A2_ = lds + 32768;
  u16* B2_ = lds + 40960;     // total 96KB

  const int t = threadIdx.x;
  // XCD-aware swizzle (nwg = 2048, divisible by 8)
  const int bid = blockIdx.x;
  const int cpx = gridDim.x >> 3;
  const int swz = (bid & 7) * cpx + (bid >> 3);
  const int n0 = (swz & 63) * BN;  // 64 n-blocks
  const int m0 = (swz >> 6) * BM;

  const int lane = t & 63;
  const int wid = t >> 6;      // 0..7
  const int r32 = lane & 31;   // row/col within 32x32 tile
  const int hi1 = lane >> 5;   // k-half selector (0..1)
  const int wm = wid >> 2;     // 0..1 -> rows wm*128..+127
  const int wn = wid & 3;      // 0..3 -> cols wn*64..+63

  const u16* Ag = Xg + (size_t)m0 * K_DIM;
  const u16* Bg = Wg + (size_t)n0 * K_DIM;

  f32x16 acc[4][2] = {};       // [row-tile 0..3][col-tile 0..1]
  bf16x8 Xa[4], Xb[2];         // ks-step frag buffer X
  bf16x8 Ya[4], Yb[2];         // ks-step frag buffer Y

  // 32x32x16 operand layout (r2-verified): lane holds row/col = lane&31,
  // k = (lane>>5)*8 + j -> k-unit ku = s*2 + hi1 for ks-step s.
#define RD(F, RA, RB, S_)                                                      \
  do {                                                                         \
    _Pragma("unroll") for (int rt = 0; rt < 4; ++rt)                           \
        F##a[rt] = frag32(RA, wm * 128 + rt * 32 + r32, (S_) * 2 + hi1);       \
    _Pragma("unroll") for (int ct = 0; ct < 2; ++ct)                           \
        F##b[ct] = frag32(RB, wn * 64 + ct * 32 + r32, (S_) * 2 + hi1);        \
  } while (0)

#define MM(F)                                                                  \
  do {                                                                         \
    __builtin_amdgcn_s_setprio(1);                                             \
    _Pragma("unroll") for (int rt = 0; rt < 4; ++rt)                           \
    _Pragma("unroll") for (int ct = 0; ct < 2; ++ct)                           \
        acc[rt][ct] = __builtin_amdgcn_mfma_f32_32x32x16_bf16(                 \
            F##a[rt], F##b[ct], acc[rt][ct], 0, 0, 0);                         \
    __builtin_amdgcn_s_setprio(0);                                             \
  } while (0)

#define INTERVAL(RA, RB, SA2, SB2, TN, ST)                                     \
  do {                                                                         \
    if (ST) {                                                                  \
      stage32(Ag + (size_t)(TN) * BK, SA2, t);                                 \
      stage32(Bg + (size_t)(TN) * BK, SB2, t);                                 \
    }                                                                          \
    RD(X, RA, RB, 0);                                                          \
    RD(Y, RA, RB, 1);                                                          \
    MM(X);                                                                     \
    MM(Y);                                                                     \
    LGKMCNT(0); /* all reads of RA/RB drained before overwrite window */       \
    if (ST) {                                                                  \
      VMCNT(4); /* tile u+1 resident; u+2's 4 loads stay in flight */          \
    } else {                                                                   \
      VMCNT(0); /* tail only (last 2 tiles) */                                 \
    }                                                                          \
    BARRIER();                                                                 \
  } while (0)

  // ---- prologue: stage tiles 0,1
  stage32(Ag, A0_, t);
  stage32(Bg, B0_, t);
  stage32(Ag + BK, A1_, t);
  stage32(Bg + BK, B1_, t);
  VMCNT(4);  // tile 0 landed (own 4); tile 1's 4 in flight
  BARRIER();

  // ---- main loop: 42 x 3 tiles (0..125), then tail tiles 126,127
  for (int j = 0; j < 42; ++j) {
    const int tb = 3 * j;
    INTERVAL(A0_, B0_, A2_, B2_, tb + 2, true);
    INTERVAL(A1_, B1_, A0_, B0_, tb + 3, true);
    INTERVAL(A2_, B2_, A1_, B1_, tb + 4, (tb + 4) < NT);
  }
  INTERVAL(A0_, B0_, A2_, B2_, 0, false);  // tile 126
  INTERVAL(A1_, B1_, A2_, B2_, 0, false);  // tile 127

  // ---- epilogue: y = acc * scale[n] + bias[n], f32 store
  // 32x32 C/D layout (r2-verified): col = lane&31,
  // row = (reg&3) + 8*(reg>>2) + 4*(lane>>5)
#pragma unroll
  for (int ct = 0; ct < 2; ++ct) {
    int n = n0 + wn * 64 + ct * 32 + r32;
    float sc = S[n];
    float bv = Bv[n];
#pragma unroll
    for (int mi = 0; mi < 4; ++mi) {
#pragma unroll
      for (int reg = 0; reg < 16; ++reg) {
        int m = m0 + wm * 128 + mi * 32 + (reg & 3) + 8 * (reg >> 2) + 4 * hi1;
        Y[(size_t)m * N_DIM + n] = acc[mi][ct][reg] * sc + bv;
      }
    }
  }
#undef INTERVAL
#undef MM
#undef RD
}

// ---- fallback (ws too small / shape mismatch): serial 128^2 with inline
// convert
__global__ __launch_bounds__(256) void qgemm_fb_kernel(
    const float* __restrict__ Xf, const int* __restrict__ Wi,
    const float* __restrict__ S, const float* __restrict__ Bv,
    float* __restrict__ Y, int M) {
  __shared__ u16 As[128 * 64];
  __shared__ u16 Bs[128 * 64];
  const int t = threadIdx.x;
  const int bid = blockIdx.x;
  const int n0 = (bid & 127) * 128;
  const int m0 = (bid >> 7) * 128;
  const int lane = t & 63;
  const int wid = t >> 6;
  const int r16 = lane & 15;
  const int hi4 = lane >> 4;
  const int wm = wid >> 1;
  const int wn = wid & 1;
  f32x4 acc[4][4] = {};
  for (int kt = 0; kt < K_DIM; kt += 64) {
#pragma unroll
    for (int c = 0; c < 8; ++c) {
      int h = c * 1024 + t * 4;
      int row = h >> 6;
      int col = h & 63;
      float4 v = *(const float4*)(Xf + (size_t)(m0 + row) * K_DIM + kt + col);
      ushort4 o;
      o.x = f32_to_bf16(v.x); o.y = f32_to_bf16(v.y);
      o.z = f32_to_bf16(v.z); o.w = f32_to_bf16(v.w);
      *(ushort4*)&As[h] = o;
      int4 w = *(const int4*)(Wi + (size_t)(n0 + row) * K_DIM + kt + col);
      ushort4 ow;
      ow.x = i32_to_bf16(w.x); ow.y = i32_to_bf16(w.y);
      ow.z = i32_to_bf16(w.z); ow.w = i32_to_bf16(w.w);
      *(ushort4*)&Bs[h] = ow;
    }
    __syncthreads();
#pragma unroll
    for (int kk = 0; kk < 64; kk += 32) {
      bf16x8 af[4], bf[4];
#pragma unroll
      for (int mi = 0; mi < 4; ++mi)
        af[mi] = *(const bf16x8*)&As[(wm * 64 + mi * 16 + r16) * 64 + kk + hi4 * 8];
#pragma unroll
      for (int ni = 0; ni < 4; ++ni)
        bf[ni] = *(const bf16x8*)&Bs[(wn * 64 + ni * 16 + r16) * 64 + kk + hi4 * 8];
#pragma unroll
      for (int mi = 0; mi < 4; ++mi)
#pragma unroll
        for (int ni = 0; ni < 4; ++ni)
          acc[mi][ni] = __builtin_amdgcn_mfma_f32_16x16x32_bf16(
              af[mi], bf[ni], acc[mi][ni], 0, 0, 0);
    }
    __syncthreads();
  }
#pragma unroll
  for (int ni = 0; ni < 4; ++ni) {
    int n = n0 + wn * 64 + ni * 16 + r16;
    float sc = S[n], bv = Bv[n];
#pragma unroll
    for (int mi = 0; mi < 4; ++mi)
#pragma unroll
      for (int r = 0; r < 4; ++r) {
        int m = m0 + wm * 64 + mi * 16 + hi4 * 4 + r;
        Y[(size_t)m * N_DIM + n] = acc[mi][ni][r] * sc + bv;
      }
  }
}

extern "C" void kernel_launch(void* const* d_in, const int* in_sizes, int n_in,
                              void* d_out, int out_size, void* d_ws,
                              size_t ws_size, hipStream_t stream) {
  const float* x = (const float*)d_in[0];  // fp16 promoted to f32 by harness
  const int* wgt = (const int*)d_in[1];    // int8 promoted to int32
  const float* s = (const float*)d_in[2];
  const float* b = (const float*)d_in[3];
  float* y = (float*)d_out;

  const int M = in_sizes[0] / K_DIM;  // 8192
  const size_t wcount = (size_t)N_DIM * K_DIM;
  const size_t xcount = (size_t)in_sizes[0];
  const size_t need = (wcount + xcount) * sizeof(u16);

  if (ws_size >= need && (M % BM) == 0) {
    u16* wb = (u16*)d_ws;
    u16* xb = wb + wcount;
    wconvert_kernel<<<2048, 256, 0, stream>>>(wgt, wb, (int)(wcount / 4));
    xconvert_kernel<<<2048, 256, 0, stream>>>(x, xb, (int)(xcount / 4));
    hipFuncSetAttribute((const void*)qgemm8_kernel,
                        hipFuncAttributeMaxDynamicSharedMemorySize, 98304);
    dim3 grid((N_DIM / BN) * (M / BM));  // 2048
    qgemm8_kernel<<<grid, 512, 98304, stream>>>(xb, wb, s, b, y, M);
  } else {
    dim3 grid((N_DIM / 128) * (M / 128));
    qgemm_fb_kernel<<<grid, 256, 0, stream>>>(x, wgt, s, b, y, M);
  }
}

// Round 8
// 1079.051 us; speedup vs baseline: 1.1674x; 1.0759x over previous
//
#include <hip/hip_runtime.h>
#include <hip/hip_bf16.h>
#include <stdint.h>

typedef unsigned short u16;

#define K_DIM 4096
#define N_DIM 16384

// ---- 8-phase 256^2 geometry (r2-verified, best = 1009 us)
#define BM 256
#define BN 256
#define BK 64
#define NT (K_DIM / BK)  // 64 K-tiles
#define HALF_ELEMS 8192  // 128 rows * 64 cols

typedef __attribute__((ext_vector_type(4))) float f32x4;
typedef __attribute__((ext_vector_type(16))) float f32x16;
typedef __attribute__((ext_vector_type(8))) short bf16x8;

#define GLOAD_LDS16(g, l)                                                      \
  __builtin_amdgcn_global_load_lds(                                            \
      (const __attribute__((address_space(1))) void*)(g),                      \
      (__attribute__((address_space(3))) void*)(l), 16, 0, 0)

#define CFENCE() asm volatile("" ::: "memory")
// No sched_barrier(0) pins (round-7 change, re-tested here after fixing the
// P4 QUAD typo that invalidated round 7). The "memory" clobbers still order
// all LDS/VMEM ops across the barrier (WAR/RAW preserved); MFMAs depend on
// ds_read results via SSA dataflow so the compiler's own counted waits apply.
#define BARRIER()                                                              \
  do {                                                                         \
    CFENCE();                                                                  \
    __builtin_amdgcn_s_barrier();                                              \
    CFENCE();                                                                  \
  } while (0)
#define VMCNT(n) asm volatile("s_waitcnt vmcnt(" #n ")" ::: "memory")

// int32 in [-127,127] -> bf16 exact
__device__ __forceinline__ u16 i32_to_bf16(int v) {
  return (u16)(__float_as_uint((float)v) >> 16);
}
__device__ __forceinline__ u16 f32_to_bf16(float f) {
  __hip_bfloat16 h = __float2bfloat16(f);
  return *(u16*)&h;
}

__global__ void wconvert_kernel(const int* __restrict__ w,
                                u16* __restrict__ out, int n4) {
  int idx = blockIdx.x * blockDim.x + threadIdx.x;
  int stride = gridDim.x * blockDim.x;
  const int4* w4 = (const int4*)w;
  ushort4* o4 = (ushort4*)out;
  for (int i = idx; i < n4; i += stride) {
    int4 v = w4[i];
    ushort4 o;
    o.x = i32_to_bf16(v.x);
    o.y = i32_to_bf16(v.y);
    o.z = i32_to_bf16(v.z);
    o.w = i32_to_bf16(v.w);
    o4[i] = o;
  }
}

__global__ void xconvert_kernel(const float* __restrict__ x,
                                u16* __restrict__ out, int n4) {
  int idx = blockIdx.x * blockDim.x + threadIdx.x;
  int stride = gridDim.x * blockDim.x;
  const float4* x4 = (const float4*)x;
  ushort4* o4 = (ushort4*)out;
  for (int i = idx; i < n4; i += stride) {
    float4 v = x4[i];
    ushort4 o;
    o.x = f32_to_bf16(v.x);
    o.y = f32_to_bf16(v.y);
    o.z = f32_to_bf16(v.z);
    o.w = f32_to_bf16(v.w);
    o4[i] = o;
  }
}

// Stage one half-tile (128 rows x 64 k, bf16, 16KB) global->LDS.
// LDS dest is LINEAR (gload_lds writes base + lane*16); the st-swizzle is
// applied by permuting the GLOBAL source 16B-unit:
//   stored unit at LDS slot (row, lin) = lin ^ sigma(row),
//   sigma(row) = (row ^ (row>>2)) & 7  (r2-verified conflict-free: 0 cnt)
__device__ __forceinline__ void stage_half(const u16* __restrict__ src,
                                           u16* lds_half, int t) {
#pragma unroll
  for (int c = 0; c < 2; ++c) {
    int e = c * 4096 + t * 8;                 // per-lane linear u16 offset
    int row = c * 64 + (t >> 3);              // 0..127
    int usw = (t & 7) ^ (((t >> 3) ^ (t >> 5)) & 7);  // lin ^ sigma(row)
    int base = __builtin_amdgcn_readfirstlane(e);  // wave-uniform LDS base
    GLOAD_LDS16(src + (size_t)row * K_DIM + usw * 8, lds_half + base);
  }
}

// swizzled fragment read: tile row r (0..255), 16B-unit u (0..7)
__device__ __forceinline__ bf16x8 frag(const u16* sbuf, int r, int u) {
  return *(const bf16x8*)&sbuf[r * 64 + ((u ^ ((r ^ (r >> 2)) & 7)) << 3)];
}

// C[M,N] = X[M,K] * W[N,K]^T ; y = acc*scale[n] + bias[n], f32 out.
// 256x256 tile, BK=64, 8 waves (2M x 4N), per-wave 128x64 output,
// 8-phase K-loop (2 K-tiles/iter), counted vmcnt(6), setprio, src-swizzled
// LDS, 32x32x16 MFMA (4x2 grid, acc = 8 x f32x16). Identical to the r2
// kernel except the barrier macro carries no sched_barrier(0) pins.
__global__ __launch_bounds__(512, 2) void qgemm8_kernel(
    const u16* __restrict__ Xb,   // bf16 [M][K]
    const u16* __restrict__ Wb,   // bf16 [N][K]
    const float* __restrict__ S,  // f32 [N]
    const float* __restrict__ Bv, // f32 [N]
    float* __restrict__ Y,        // f32 [M][N]
    int M) {
  extern __shared__ u16 lds[];
  u16* sA0 = lds;             // buf0 A [256][64]
  u16* sB0 = lds + 16384;     // buf0 B
  u16* sA1 = lds + 32768;     // buf1 A
  u16* sB1 = lds + 49152;     // buf1 B

  const int t = threadIdx.x;
  // XCD-aware swizzle (nwg = 2048, divisible by 8)
  const int bid = blockIdx.x;
  const int cpx = gridDim.x >> 3;
  const int swz = (bid & 7) * cpx + (bid >> 3);
  const int n0 = (swz & 63) * BN;  // 64 n-blocks
  const int m0 = (swz >> 6) * BM;

  const int lane = t & 63;
  const int wid = t >> 6;   // 0..7
  const int r32 = lane & 31;   // row/col within 32x32 tile
  const int hi1 = lane >> 5;   // k-half selector (0..1)
  const int wm = wid >> 2;  // 0..1 -> rows wm*128..+127
  const int wn = wid & 3;   // 0..3 -> cols wn*64..+63

  const u16* Asrc = Xb + (size_t)m0 * K_DIM;
  const u16* Bsrc = Wb + (size_t)n0 * K_DIM;

  f32x16 acc[4][2] = {};  // [row-tile 0..3][col-tile 0..1]
  bf16x8 aT[8], bT[8];    // [rt*4+ks] / [ct*4+ks], ks = 0..3 (K=16 steps)

  // 32x32x16 operand layout (r2-verified): lane holds row/col = lane&31,
  // k = (lane>>5)*8 + j  -> 16B unit u = ks*2 + hi1 within the 64-k row.
#define LOAD_B(sb)                                                             \
  _Pragma("unroll") for (int ct = 0; ct < 2; ++ct)                             \
  _Pragma("unroll") for (int ks = 0; ks < 4; ++ks)                             \
      bT[ct * 4 + ks] = frag(sb, wn * 64 + ct * 32 + r32, ks * 2 + hi1);

#define LOAD_A(sa, HB)                                                         \
  _Pragma("unroll") for (int rt = 0; rt < 2; ++rt)                             \
  _Pragma("unroll") for (int ks = 0; ks < 4; ++ks)                             \
      aT[rt * 4 + ks] =                                                        \
          frag(sa, wm * 128 + ((HB) + rt) * 32 + r32, ks * 2 + hi1);

// one quadrant: 64 rows (HB half) x 32 cols (CT) x K=64 -> 8 MFMAs
// HB in {0,2}, CT in {0,1} ONLY (acc is [4][2]; HB+rt <= 3).
#define QUAD(HB, CT)                                                           \
  do {                                                                         \
    __builtin_amdgcn_s_setprio(1);                                             \
    _Pragma("unroll") for (int ks = 0; ks < 4; ++ks)                           \
    _Pragma("unroll") for (int rt = 0; rt < 2; ++rt)                           \
        acc[(HB) + rt][CT] =                                                   \
            __builtin_amdgcn_mfma_f32_32x32x16_bf16(                           \
                aT[rt * 4 + ks], bT[(CT) * 4 + ks], acc[(HB) + rt][CT],        \
                0, 0, 0);                                                      \
    __builtin_amdgcn_s_setprio(0);                                             \
  } while (0)

  // ---- prologue: stage T0 fully (4 halves), then T1's B0,B1,A0 (3 halves)
  stage_half(Bsrc, sB0, t);
  stage_half(Bsrc + 128 * K_DIM, sB0 + HALF_ELEMS, t);
  stage_half(Asrc, sA0, t);
  stage_half(Asrc + 128 * K_DIM, sA0 + HALF_ELEMS, t);
  VMCNT(4);
  stage_half(Bsrc + BK, sB1, t);
  stage_half(Bsrc + 128 * K_DIM + BK, sB1 + HALF_ELEMS, t);
  stage_half(Asrc + BK, sA1, t);
  VMCNT(6);  // T0's 4 halves landed; 3 halves (T1 partial) in flight
  BARRIER();

  // ---- main loop: iteration i computes K-tiles 2i (buf0) and 2i+1 (buf1)
  for (int i = 0; i < NT / 2; ++i) {
    const int t1k = (2 * i + 1) * BK;
    const int tn0k = (2 * i + 2) * BK;
    const int tn1k = (2 * i + 3) * BK;
    const bool gn0 = (2 * i + 2) < NT;
    const bool gn1 = (2 * i + 3) < NT;

    // P1: all B + A-lo of T0(buf0); stage A1 of T1 -> buf1
    LOAD_B(sB0);
    LOAD_A(sA0, 0);
    stage_half(Asrc + 128 * K_DIM + t1k, sA1 + HALF_ELEMS, t);
    BARRIER();
    QUAD(0, 0);
    BARRIER();

    // P2: stage B0 of Tn0 -> buf0 (B(buf0) LDS dead after P1)
    if (gn0) stage_half(Bsrc + tn0k, sB0, t);
    BARRIER();
    QUAD(0, 1);
    BARRIER();

    // P3: A-hi of T0; stage B1 of Tn0
    LOAD_A(sA0, 2);
    if (gn0) stage_half(Bsrc + 128 * K_DIM + tn0k, sB0 + HALF_ELEMS, t);
    BARRIER();
    QUAD(2, 0);
    BARRIER();

    // P4: stage A0 of Tn0 (A(buf0) dead after P3); counted drain after MFMAs
    if (gn0) stage_half(Asrc + tn0k, sA0, t);
    BARRIER();
    QUAD(2, 1);  // (round-7 bug was QUAD(4,2) here -- OOB acc; fixed)
    if (gn0) {
      VMCNT(6);  // guarantees T1 fully resident (incl. P1's A1)
    } else {
      VMCNT(0);  // tail: nothing counted behind, drain fully
    }
    BARRIER();

    // P5: all B + A-lo of T1(buf1); stage A1 of Tn0 -> buf0
    LOAD_B(sB1);
    LOAD_A(sA1, 0);
    if (gn0) stage_half(Asrc + 128 * K_DIM + tn0k, sA0 + HALF_ELEMS, t);
    BARRIER();
    QUAD(0, 0);
    BARRIER();

    // P6: stage B0 of Tn1 -> buf1 (B(buf1) dead after P5)
    if (gn1) stage_half(Bsrc + tn1k, sB1, t);
    BARRIER();
    QUAD(0, 1);
    BARRIER();

    // P7: A-hi of T1; stage B1 of Tn1
    LOAD_A(sA1, 2);
    if (gn1) stage_half(Bsrc + 128 * K_DIM + tn1k, sB1 + HALF_ELEMS, t);
    BARRIER();
    QUAD(2, 0);
    BARRIER();

    // P8: stage A0 of Tn1 (A(buf1) dead after P7); counted drain after MFMAs
    if (gn1) stage_half(Asrc + tn1k, sA1, t);
    BARRIER();
    QUAD(2, 1);
    if (gn1) {
      VMCNT(6);  // guarantees Tn0 fully resident for next iteration
    } else {
      VMCNT(0);
    }
    BARRIER();
  }

  // ---- epilogue: y = acc * scale[n] + bias[n], f32 store
  // 32x32 C/D layout (r2-verified): col = lane&31,
  // row = (reg&3) + 8*(reg>>2) + 4*(lane>>5)
#pragma unroll
  for (int ct = 0; ct < 2; ++ct) {
    int n = n0 + wn * 64 + ct * 32 + r32;
    float sc = S[n];
    float bv = Bv[n];
#pragma unroll
    for (int mi = 0; mi < 4; ++mi) {
#pragma unroll
      for (int reg = 0; reg < 16; ++reg) {
        int m = m0 + wm * 128 + mi * 32 + (reg & 3) + 8 * (reg >> 2) + 4 * hi1;
        Y[(size_t)m * N_DIM + n] = acc[mi][ct][reg] * sc + bv;
      }
    }
  }
#undef LOAD_A
#undef LOAD_B
#undef QUAD
}

// ---- fallback (ws too small): serial 128^2 with inline convert
__global__ __launch_bounds__(256) void qgemm_fb_kernel(
    const float* __restrict__ Xf, const int* __restrict__ Wi,
    const float* __restrict__ S, const float* __restrict__ Bv,
    float* __restrict__ Y, int M) {
  __shared__ u16 As[128 * 64];
  __shared__ u16 Bs[128 * 64];
  const int t = threadIdx.x;
  const int bid = blockIdx.x;
  const int n0 = (bid & 127) * 128;
  const int m0 = (bid >> 7) * 128;
  const int lane = t & 63;
  const int wid = t >> 6;
  const int r16 = lane & 15;
  const int hi4 = lane >> 4;
  const int wm = wid >> 1;
  const int wn = wid & 1;
  f32x4 acc[4][4] = {};
  for (int kt = 0; kt < K_DIM; kt += 64) {
#pragma unroll
    for (int c = 0; c < 8; ++c) {
      int h = c * 1024 + t * 4;
      int row = h >> 6;
      int col = h & 63;
      float4 v = *(const float4*)(Xf + (size_t)(m0 + row) * K_DIM + kt + col);
      ushort4 o;
      o.x = f32_to_bf16(v.x); o.y = f32_to_bf16(v.y);
      o.z = f32_to_bf16(v.z); o.w = f32_to_bf16(v.w);
      *(ushort4*)&As[h] = o;
      int4 w = *(const int4*)(Wi + (size_t)(n0 + row) * K_DIM + kt + col);
      ushort4 ow;
      ow.x = i32_to_bf16(w.x); ow.y = i32_to_bf16(w.y);
      ow.z = i32_to_bf16(w.z); ow.w = i32_to_bf16(w.w);
      *(ushort4*)&Bs[h] = ow;
    }
    __syncthreads();
#pragma unroll
    for (int kk = 0; kk < 64; kk += 32) {
      bf16x8 af[4], bf[4];
#pragma unroll
      for (int mi = 0; mi < 4; ++mi)
        af[mi] = *(const bf16x8*)&As[(wm * 64 + mi * 16 + r16) * 64 + kk + hi4 * 8];
#pragma unroll
      for (int ni = 0; ni < 4; ++ni)
        bf[ni] = *(const bf16x8*)&Bs[(wn * 64 + ni * 16 + r16) * 64 + kk + hi4 * 8];
#pragma unroll
      for (int mi = 0; mi < 4; ++mi)
#pragma unroll
        for (int ni = 0; ni < 4; ++ni)
          acc[mi][ni] = __builtin_amdgcn_mfma_f32_16x16x32_bf16(
              af[mi], bf[ni], acc[mi][ni], 0, 0, 0);
    }
    __syncthreads();
  }
#pragma unroll
  for (int ni = 0; ni < 4; ++ni) {
    int n = n0 + wn * 64 + ni * 16 + r16;
    float sc = S[n], bv = Bv[n];
#pragma unroll
    for (int mi = 0; mi < 4; ++mi)
#pragma unroll
      for (int r = 0; r < 4; ++r) {
        int m = m0 + wm * 64 + mi * 16 + hi4 * 4 + r;
        Y[(size_t)m * N_DIM + n] = acc[mi][ni][r] * sc + bv;
      }
  }
}

extern "C" void kernel_launch(void* const* d_in, const int* in_sizes, int n_in,
                              void* d_out, int out_size, void* d_ws,
                              size_t ws_size, hipStream_t stream) {
  const float* x = (const float*)d_in[0];  // fp16 promoted to f32 by harness
  const int* wgt = (const int*)d_in[1];    // int8 promoted to int32
  const float* s = (const float*)d_in[2];
  const float* b = (const float*)d_in[3];
  float* y = (float*)d_out;

  const int M = in_sizes[0] / K_DIM;  // 8192
  const size_t wcount = (size_t)N_DIM * K_DIM;
  const size_t xcount = (size_t)in_sizes[0];
  const size_t need = (wcount + xcount) * sizeof(u16);

  if (ws_size >= need && (M % BM) == 0) {
    u16* wb = (u16*)d_ws;
    u16* xb = wb + wcount;
    wconvert_kernel<<<2048, 256, 0, stream>>>(wgt, wb, (int)(wcount / 4));
    xconvert_kernel<<<2048, 256, 0, stream>>>(x, xb, (int)(xcount / 4));
    hipFuncSetAttribute((const void*)qgemm8_kernel,
                        hipFuncAttributeMaxDynamicSharedMemorySize, 131072);
    dim3 grid((N_DIM / BN) * (M / BM));  // 2048
    qgemm8_kernel<<<grid, 512, 131072, stream>>>(xb, wb, s, b, y, M);
  } else {
    dim3 grid((N_DIM / 128) * (M / 128));
    qgemm_fb_kernel<<<grid, 256, 0, stream>>>(x, wgt, s, b, y, M);
  }
}